// Round 3
// baseline (1459.722 us; speedup 1.0000x reference)
//
#include <hip/hip_runtime.h>
#include <stdint.h>

#define B_  32
#define T_  64
#define V_  32000
#define E_  256
#define H_  512
#define TS  63

typedef __attribute__((ext_vector_type(8))) short short8;
typedef __attribute__((ext_vector_type(4))) float floatx4;

union U16c { uint4 u; short8 s; };

__device__ __forceinline__ short8 ld8(const unsigned short* p) {
    U16c x; x.u = *(const uint4*)p; return x.s;
}

__device__ __forceinline__ unsigned short f2bf(float f) {
    union { float f; unsigned u; } v; v.f = f;
    unsigned r = v.u + 0x7FFFu + ((v.u >> 16) & 1u);
    return (unsigned short)(r >> 16);
}

// ---------------- setup: convert W_proj to bf16 ----------------
__global__ void k_cvt_wp(const float* __restrict__ wp, unsigned short* __restrict__ dst) {
    int i = blockIdx.x * blockDim.x + threadIdx.x;
    const float4* s = (const float4*)wp + (size_t)i * 2;
    float4 a = s[0], b = s[1];
    union { uint4 u; unsigned short h[8]; } o;
    o.h[0] = f2bf(a.x); o.h[1] = f2bf(a.y); o.h[2] = f2bf(a.z); o.h[3] = f2bf(a.w);
    o.h[4] = f2bf(b.x); o.h[5] = f2bf(b.y); o.h[6] = f2bf(b.z); o.h[7] = f2bf(b.w);
    ((uint4*)dst)[i] = o.u;
}

// ---------------- setup: W_ih/W_hh bf16, emb gather, h0 row, flags ----------------
__global__ void k_setup(const float* __restrict__ wih, const float* __restrict__ whh,
                        const float* __restrict__ embt, const int* __restrict__ trg,
                        const float* __restrict__ h0,
                        unsigned short* __restrict__ wih_bf, unsigned short* __restrict__ whh_bf,
                        unsigned short* __restrict__ emb_bf, unsigned short* __restrict__ hall,
                        unsigned* __restrict__ fl)
{
    const int NIH = (3 * H_ * E_) / 4;   // 98304
    const int NHH = (3 * H_ * H_) / 4;   // 196608
    const int NEMB = TS * B_ * E_ / 4;   // 129024
    const int NH0 = B_ * H_ / 4;         // 4096
    int i = blockIdx.x * blockDim.x + threadIdx.x;
    if (i < NIH + NHH) {
        const float* src; unsigned short* dst; int j;
        if (i < NIH) { src = wih; dst = wih_bf; j = i; }
        else         { src = whh; dst = whh_bf; j = i - NIH; }
        float4 v = ((const float4*)src)[j];
        union { unsigned long long u; unsigned short h[4]; } o;
        o.h[0] = f2bf(v.x); o.h[1] = f2bf(v.y); o.h[2] = f2bf(v.z); o.h[3] = f2bf(v.w);
        ((unsigned long long*)dst)[j] = o.u;
        return;
    }
    i -= NIH + NHH;
    if (i < NEMB) {
        int r = i >> 6, c = i & 63;
        int tt = r >> 5, b = r & 31;
        int tok = trg[b * T_ + tt];
        float4 v = ((const float4*)(embt + (size_t)tok * E_))[c];
        union { unsigned long long u; unsigned short h[4]; } o;
        o.h[0] = f2bf(v.x); o.h[1] = f2bf(v.y); o.h[2] = f2bf(v.z); o.h[3] = f2bf(v.w);
        ((unsigned long long*)(emb_bf + (size_t)r * E_))[c] = o.u;
        return;
    }
    i -= NEMB;
    if (i < NH0) {
        float4 v = ((const float4*)h0)[i];
        union { unsigned long long u; unsigned short h[4]; } o;
        o.h[0] = f2bf(v.x); o.h[1] = f2bf(v.y); o.h[2] = f2bf(v.z); o.h[3] = f2bf(v.w);
        ((unsigned long long*)hall)[i] = o.u;
        return;
    }
    i -= NH0;
    if (i < 2048) fl[i] = 0;     // 64 steps x 32 block-flag dwords
}

// ---------------- x_gates GEMM: xg = emb_bf @ W_ih^T + b_ih ----------------
// M=2048 (2016 real), N=1536, K=256. 128x128 tile, BK=32.
__global__ __launch_bounds__(256) void k_xg(const unsigned short* __restrict__ A,
                                            const unsigned short* __restrict__ Bm,
                                            const float* __restrict__ bias,
                                            float* __restrict__ out)
{
    __shared__ unsigned short As[128 * 32];
    __shared__ unsigned short Bs[128 * 32];
    int m0 = blockIdx.x * 128, n0 = blockIdx.y * 128;
    int tid = threadIdx.x;
    int lane = tid & 63, w = tid >> 6;
    int wm = (w & 1) * 64, wn = (w >> 1) * 64;
    int row = lane & 15, quad = lane >> 4;
    int srow = lane >> 2, skc = lane & 3;
    floatx4 acc[4][4];
    #pragma unroll
    for (int a = 0; a < 4; ++a)
        #pragma unroll
        for (int b = 0; b < 4; ++b) acc[a][b] = (floatx4){0.f, 0.f, 0.f, 0.f};

    for (int k0 = 0; k0 < E_; k0 += 32) {
        if (k0) __syncthreads();
        #pragma unroll
        for (int p = 0; p < 2; ++p) {
            int seg = w * 2 + p;
            int m = seg * 16 + srow;
            __builtin_amdgcn_global_load_lds(
                (const __attribute__((address_space(1))) void*)(A + (size_t)(m0 + m) * E_ + k0 + skc * 8),
                (__attribute__((address_space(3))) void*)(As + seg * 512),
                16, 0, 0);
            __builtin_amdgcn_global_load_lds(
                (const __attribute__((address_space(1))) void*)(Bm + (size_t)(n0 + m) * E_ + k0 + skc * 8),
                (__attribute__((address_space(3))) void*)(Bs + seg * 512),
                16, 0, 0);
        }
        __syncthreads();
        short8 af[4], bf[4];
        #pragma unroll
        for (int mi2 = 0; mi2 < 4; ++mi2)
            af[mi2] = ld8(As + (wm + mi2 * 16 + row) * 32 + quad * 8);
        #pragma unroll
        for (int ni = 0; ni < 4; ++ni)
            bf[ni] = ld8(Bs + (wn + ni * 16 + row) * 32 + quad * 8);
        #pragma unroll
        for (int mi2 = 0; mi2 < 4; ++mi2)
            #pragma unroll
            for (int ni = 0; ni < 4; ++ni)
                acc[mi2][ni] = __builtin_amdgcn_mfma_f32_16x16x32_bf16(af[mi2], bf[ni], acc[mi2][ni], 0, 0, 0);
    }
    #pragma unroll
    for (int ni = 0; ni < 4; ++ni) {
        int n = n0 + wn + ni * 16 + row;
        float bp = bias[n];
        #pragma unroll
        for (int mi2 = 0; mi2 < 4; ++mi2) {
            #pragma unroll
            for (int v = 0; v < 4; ++v) {
                int m = m0 + wm + mi2 * 16 + quad * 4 + v;
                out[(size_t)m * 1536 + n] = acc[mi2][ni][v] + bp;
            }
        }
    }
}

// ---------------- GRU recurrence: 32 blocks x 448 threads ----------------
// Waves 0..5: MFMA (reg-resident W_hh, direct coherent A-frag loads).
// Waves 0..3: elementwise (2 h-dims each) + per-wave flag byte.
// Wave 6: concurrent poller of remote block flags. 2 barriers/step.
__global__ __launch_bounds__(448, 1) void k_gru(
    const unsigned short* __restrict__ whh_bf,
    const float* __restrict__ xg,       // [2016+][1536], b_ih folded in
    const float* __restrict__ bhh, const float* __restrict__ h0,
    unsigned short* __restrict__ hall, unsigned* __restrict__ fl)
{
    __shared__ float gh[32][52];
    unsigned* hallw = (unsigned*)hall;
    int blk = blockIdx.x, tid = threadIdx.x;
    int lane = tid & 63, w = tid >> 6;
    int mi = w & 1, gi = w >> 1;               // valid for w<6
    int row = lane & 15, quad = lane >> 4;

    // ---- weight preload: 16 reg-resident B-frags per MFMA wave ----
    short8 wfrag[16];
    if (w < 6) {
        const unsigned short* wrow = whh_bf + (size_t)(gi * H_ + blk * 16 + row) * H_;
        #pragma unroll
        for (int kk = 0; kk < 16; ++kk) wfrag[kk] = ld8(wrow + kk * 32 + quad * 8);
    }

    // ---- elementwise state: thread handles (b=tid>>3, j pair (tid&7)*2) ----
    int pb = tid >> 3, pj0 = (tid & 7) * 2;
    int gj0 = blk * 16 + pj0;
    float hc0 = 0.f, hc1 = 0.f;
    float bhr0 = 0, bhr1 = 0, bhz0 = 0, bhz1 = 0, bhn0 = 0, bhn1 = 0;
    if (tid < 256) {
        hc0 = h0[pb * H_ + gj0]; hc1 = h0[pb * H_ + gj0 + 1];
        bhr0 = bhh[gj0];          bhr1 = bhh[gj0 + 1];
        bhz0 = bhh[H_ + gj0];     bhz1 = bhh[H_ + gj0 + 1];
        bhn0 = bhh[2 * H_ + gj0]; bhn1 = bhh[2 * H_ + gj0 + 1];
    }

    for (int t = 0; t < TS; ++t) {
        // xg prefetch (issues during MFMA phase; independent of h)
        float2 xr2, xz2, xn2;
        if (tid < 256) {
            const float* xrow = xg + (size_t)(t * B_ + pb) * 1536;
            xr2 = *(const float2*)(xrow + gj0);
            xz2 = *(const float2*)(xrow + 512 + gj0);
            xn2 = *(const float2*)(xrow + 1024 + gj0);
        }
        if (w < 6) {
            int b_ = mi * 16 + row;
            const unsigned* hrow = hallw + ((size_t)t * B_ + b_) * (H_ / 2);
            unsigned hv[16][4];
            #pragma unroll
            for (int kk = 0; kk < 16; ++kk)
                #pragma unroll
                for (int q = 0; q < 4; ++q)
                    hv[kk][q] = __hip_atomic_load(hrow + kk * 16 + quad * 4 + q,
                                    __ATOMIC_RELAXED, __HIP_MEMORY_SCOPE_AGENT);
            floatx4 ah = {0.f, 0.f, 0.f, 0.f};
            #pragma unroll
            for (int kk = 0; kk < 16; ++kk) {
                U16c c; c.u.x = hv[kk][0]; c.u.y = hv[kk][1]; c.u.z = hv[kk][2]; c.u.w = hv[kk][3];
                ah = __builtin_amdgcn_mfma_f32_16x16x32_bf16(c.s, wfrag[kk], ah, 0, 0, 0);
            }
            int cb = mi * 16 + quad * 4, cn = gi * 16 + row;
            #pragma unroll
            for (int v = 0; v < 4; ++v) gh[cb + v][cn] = ah[v];
        }
        __syncthreads();
        if (tid < 256) {
            float hr0 = gh[pb][pj0],      hr1 = gh[pb][pj0 + 1];
            float hz0 = gh[pb][16 + pj0], hz1 = gh[pb][16 + pj0 + 1];
            float hn0 = gh[pb][32 + pj0], hn1 = gh[pb][32 + pj0 + 1];
            float r0 = 1.f / (1.f + __expf(-(xr2.x + hr0 + bhr0)));
            float r1 = 1.f / (1.f + __expf(-(xr2.y + hr1 + bhr1)));
            float z0 = 1.f / (1.f + __expf(-(xz2.x + hz0 + bhz0)));
            float z1 = 1.f / (1.f + __expf(-(xz2.y + hz1 + bhz1)));
            float n0 = tanhf(xn2.x + r0 * (hn0 + bhn0));
            float n1 = tanhf(xn2.y + r1 * (hn1 + bhn1));
            hc0 = (1.f - z0) * n0 + z0 * hc0;
            hc1 = (1.f - z1) * n1 + z1 * hc1;
            unsigned pk = (unsigned)f2bf(hc0) | ((unsigned)f2bf(hc1) << 16);
            __hip_atomic_store(hallw + ((size_t)(t + 1) * B_ + pb) * (H_ / 2) + (gj0 >> 1),
                               pk, __ATOMIC_RELAXED, __HIP_MEMORY_SCOPE_AGENT);
            // drain own wave's h stores (acked at coherent point), then post flag byte
            asm volatile("" ::: "memory");
            __builtin_amdgcn_s_waitcnt(0);
            asm volatile("" ::: "memory");
            if (lane == 0) {
                __hip_atomic_store((unsigned char*)(fl + t * 32 + blk) + w, (unsigned char)1,
                                   __ATOMIC_RELAXED, __HIP_MEMORY_SCOPE_AGENT);
            }
        }
        if (w == 6 && lane < 32 && lane != blk) {
            // remote blocks' flags; own block covered by __syncthreads after store-drain
            while (__hip_atomic_load(fl + t * 32 + lane, __ATOMIC_RELAXED,
                                     __HIP_MEMORY_SCOPE_AGENT) != 0x01010101u) { }
            asm volatile("" ::: "memory");
        }
        __syncthreads();
    }
}

// ---------------- projection GEMM: logits = Hall @ Wp^T + b_proj ----------------
__global__ __launch_bounds__(256) void k_gemm(const unsigned short* __restrict__ A,
                                              const unsigned short* __restrict__ Bm,
                                              const float* __restrict__ bias,
                                              float* __restrict__ out)
{
    __shared__ unsigned short As[128 * 32];
    __shared__ unsigned short Bs[128 * 32];
    int m0 = blockIdx.x * 128, n0 = blockIdx.y * 128;
    int tid = threadIdx.x;
    int lane = tid & 63, w = tid >> 6;
    int wm = (w & 1) * 64, wn = (w >> 1) * 64;
    int row = lane & 15, quad = lane >> 4;
    int srow = lane >> 2, skc = lane & 3;
    floatx4 acc[4][4];
    #pragma unroll
    for (int a = 0; a < 4; ++a)
        #pragma unroll
        for (int b = 0; b < 4; ++b) acc[a][b] = (floatx4){0.f, 0.f, 0.f, 0.f};

    for (int k0 = 0; k0 < H_; k0 += 32) {
        if (k0) __syncthreads();
        #pragma unroll
        for (int p = 0; p < 2; ++p) {
            int seg = w * 2 + p;
            int m = seg * 16 + srow;
            __builtin_amdgcn_global_load_lds(
                (const __attribute__((address_space(1))) void*)(A + (size_t)(m0 + m) * H_ + k0 + skc * 8),
                (__attribute__((address_space(3))) void*)(As + seg * 512),
                16, 0, 0);
            __builtin_amdgcn_global_load_lds(
                (const __attribute__((address_space(1))) void*)(Bm + (size_t)(n0 + m) * H_ + k0 + skc * 8),
                (__attribute__((address_space(3))) void*)(Bs + seg * 512),
                16, 0, 0);
        }
        __syncthreads();
        short8 af[4], bf[4];
        #pragma unroll
        for (int mi2 = 0; mi2 < 4; ++mi2)
            af[mi2] = ld8(As + (wm + mi2 * 16 + row) * 32 + quad * 8);
        #pragma unroll
        for (int ni = 0; ni < 4; ++ni)
            bf[ni] = ld8(Bs + (wn + ni * 16 + row) * 32 + quad * 8);
        #pragma unroll
        for (int mi2 = 0; mi2 < 4; ++mi2)
            #pragma unroll
            for (int ni = 0; ni < 4; ++ni)
                acc[mi2][ni] = __builtin_amdgcn_mfma_f32_16x16x32_bf16(af[mi2], bf[ni], acc[mi2][ni], 0, 0, 0);
    }
    #pragma unroll
    for (int ni = 0; ni < 4; ++ni) {
        int n = n0 + wn + ni * 16 + row;
        float bp = bias[n];
        #pragma unroll
        for (int mi2 = 0; mi2 < 4; ++mi2) {
            #pragma unroll
            for (int v = 0; v < 4; ++v) {
                int m = m0 + wm + mi2 * 16 + quad * 4 + v;
                int orow = (m & 31) * 64 + (m >> 5);
                out[(size_t)orow * V_ + n] = acc[mi2][ni][v] + bp;
            }
        }
    }
}

// ---------------- in-place log_softmax, one block per output row ----------------
__global__ __launch_bounds__(320) void k_lsm(float* __restrict__ out)
{
    __shared__ float red[5];
    int rown = blockIdx.x;
    int t = rown & 63;
    float4* p = (float4*)(out + (size_t)rown * V_);
    int tid = threadIdx.x;
    if (t == 0) {
        float4 z; z.x = z.y = z.z = z.w = 0.f;
        for (int i = tid; i < V_ / 4; i += 320) p[i] = z;
        return;
    }
    float4 v[25];
    #pragma unroll
    for (int jj = 0; jj < 25; ++jj) v[jj] = p[tid + jj * 320];
    float m = -3.4e38f;
    #pragma unroll
    for (int jj = 0; jj < 25; ++jj)
        m = fmaxf(m, fmaxf(fmaxf(v[jj].x, v[jj].y), fmaxf(v[jj].z, v[jj].w)));
    #pragma unroll
    for (int o = 32; o > 0; o >>= 1) m = fmaxf(m, __shfl_xor(m, o));
    if ((tid & 63) == 0) red[tid >> 6] = m;
    __syncthreads();
    m = fmaxf(fmaxf(fmaxf(red[0], red[1]), fmaxf(red[2], red[3])), red[4]);
    __syncthreads();
    float s = 0.f;
    #pragma unroll
    for (int jj = 0; jj < 25; ++jj)
        s += __expf(v[jj].x - m) + __expf(v[jj].y - m) + __expf(v[jj].z - m) + __expf(v[jj].w - m);
    #pragma unroll
    for (int o = 32; o > 0; o >>= 1) s += __shfl_xor(s, o);
    if ((tid & 63) == 0) red[tid >> 6] = s;
    __syncthreads();
    s = red[0] + red[1] + red[2] + red[3] + red[4];
    float lz = m + logf(s);
    #pragma unroll
    for (int jj = 0; jj < 25; ++jj) {
        float4 o4;
        o4.x = v[jj].x - lz; o4.y = v[jj].y - lz; o4.z = v[jj].z - lz; o4.w = v[jj].w - lz;
        p[tid + jj * 320] = o4;
    }
}

extern "C" void kernel_launch(void* const* d_in, const int* in_sizes, int n_in,
                              void* d_out, int out_size, void* d_ws, size_t ws_size,
                              hipStream_t stream) {
    const int*   trg   = (const int*)d_in[0];
    const float* h0    = (const float*)d_in[1];
    const float* embt  = (const float*)d_in[2];
    const float* wih   = (const float*)d_in[3];
    const float* whh   = (const float*)d_in[4];
    const float* bih   = (const float*)d_in[5];
    const float* bhh   = (const float*)d_in[6];
    const float* wproj = (const float*)d_in[7];
    const float* bproj = (const float*)d_in[8];
    float* out = (float*)d_out;

    char* ws = (char*)d_ws;
    size_t off = 0;
    unsigned short* wp_bf  = (unsigned short*)(ws + off); off += (size_t)V_ * H_ * 2;        // 32.77 MB
    unsigned short* wih_bf = (unsigned short*)(ws + off); off += (size_t)3 * H_ * E_ * 2;    // 0.79 MB
    unsigned short* whh_bf = (unsigned short*)(ws + off); off += (size_t)3 * H_ * H_ * 2;    // 1.57 MB
    unsigned short* emb_bf = (unsigned short*)(ws + off); off += (size_t)64 * B_ * E_ * 2;   // 1.05 MB
    unsigned short* hall   = (unsigned short*)(ws + off); off += (size_t)64 * B_ * H_ * 2;   // 2.10 MB
    float*          xg     = (float*)(ws + off);          off += (size_t)64 * B_ * 1536 * 4; // 12.58 MB
    unsigned*       fl     = (unsigned*)(ws + off);       off += 2048 * 4;                   // 8 KB

    k_cvt_wp<<<8000, 256, 0, stream>>>(wproj, wp_bf);
    k_setup<<<1680, 256, 0, stream>>>(wih, whh, embt, trg, h0,
                                      wih_bf, whh_bf, emb_bf, hall, fl);
    dim3 gx(16, 12);
    k_xg<<<gx, 256, 0, stream>>>(emb_bf, wih_bf, bih, xg);
    k_gru<<<32, 448, 0, stream>>>(whh_bf, xg, bhh, h0, hall, fl);
    dim3 gg(16, 250);
    k_gemm<<<gg, 256, 0, stream>>>(hall, wp_bf, bproj, out);
    k_lsm<<<2048, 320, 0, stream>>>(out);
}